// Round 14
// baseline (118.096 us; speedup 1.0000x reference)
//
#include <hip/hip_runtime.h>
#include <math.h>

typedef __attribute__((ext_vector_type(8))) short short8v;   // 8 bf16
typedef __attribute__((ext_vector_type(16))) float f32x16;   // MFMA acc

// ws layout:
//  ushort offsets:
//   basisF (fdft) [cc128][tbl4][kh2][m64][e8]    @ u 0        (524288 u)
//     tbl: 0=cosHi 1=cosLo 2=(-sin)Hi 3=(-sin)Lo ; t = cc*16 + kh*8 + e
//   basisI (idft) [slab4][tbl4][kh2][t1088][e8]  @ u 524288   (278528 u)
//     tbl: 0=cosHi 1=cosLo 2=sinHi 3=sinLo ; m = slab*16 + kh*8 + e
//  float offsets:
//   XP [zz8][b16][p2][h8][m64][e64]              @ f 401408   (8388608 f)
//  ushort offsets:
//   YT [b16][tbl4][ch512][m64]                   @ u 17580032 (2097152 u)
//     tbl: 0=YrHi 1=YrLo 2=YiHi 3=YiLo (Yi sign-folded)
#define BF_U 0
#define BI_U 524288
#define XP_F 401408
#define YT_U 17580032

__device__ inline unsigned short bf16_rne(float x) {
    unsigned int u = __float_as_uint(x);
    u += 0x7FFFu + ((u >> 16) & 1u);
    return (unsigned short)(u >> 16);
}
__device__ inline float bf16_f(unsigned short h) {
    return __uint_as_float(((unsigned int)h) << 16);
}

// async global->LDS, 16 B per lane; l must be wave-uniform, g per-lane.
__device__ inline void gl_lds16(const void* g, void* l) {
    __builtin_amdgcn_global_load_lds(
        (const __attribute__((address_space(1))) unsigned int*)g,
        (__attribute__((address_space(3))) unsigned int*)l, 16, 0, 0);
}

__global__ __launch_bounds__(256) void basis_kernel(float* __restrict__ w) {
    int idx = blockIdx.x * 256 + threadIdx.x;
    const float th = 0.0030679615757712823f; // 2*pi/2048
    unsigned short* bw = (unsigned short*)w;
    if (idx < 131072) {          // fdft tables: t 0..2047, m 0..63
        int t = idx >> 6, m = idx & 63;
        int j = (m * t) & 2047;
        float s, c; sincosf(th * (float)j, &s, &c);
        float ns = -s;
        int cc = t >> 4, kh = (t >> 3) & 1, e = t & 7;
        int base = BF_U + cc * 4096 + kh * 512 + m * 8 + e;
        unsigned short chv = bf16_rne(c), shv = bf16_rne(ns);
        bw[base]        = chv;
        bw[base + 1024] = bf16_rne(c - bf16_f(chv));
        bw[base + 2048] = shv;
        bw[base + 3072] = bf16_rne(ns - bf16_f(shv));
    }
    if (idx < 69632) {           // idft tables
        int m = idx / 1088, t = idx - m * 1088;
        int j = (m * t) & 2047;
        float s, c; sincosf(th * (float)j, &s, &c);
        int slab = m >> 4, kh = (m >> 3) & 1, e = m & 7;
        int base = BI_U + (slab * 8 + kh) * 8704 + t * 8 + e;
        unsigned short chv = bf16_rne(c), shv = bf16_rne(s);
        bw[base]         = chv;
        bw[base + 17408] = bf16_rne(c - bf16_f(chv));
        bw[base + 34816] = shv;
        bw[base + 52224] = bf16_rne(s - bf16_f(shv));
    }
}

// Forward (UNFOLDED) DFT via bf16-split MFMA, m97-style global_load_lds staging.
// Block: 64m x 64ch x one t-quarter; 4 waves = (m-half x ch-half).
// Per chunk (16 t): stage data 4 KB f32 + basis 8 KB bf16 via global_load_lds
// (dbuf, 1 barrier/chunk); consume via conflict-free LDS reads + 6 MFMA/wave.
// Grid (chtile8, b16, zz8) = 1024 blocks.
__global__ __launch_bounds__(256, 4) void fdft_kernel(const float* __restrict__ q,
                                                      const float* __restrict__ k,
                                                      float* __restrict__ ws) {
    const int chtile = blockIdx.x;        // 0..7 (64 ch)
    const int b      = blockIdx.y;
    const int zz     = blockIdx.z;        // tz*4 + part
    const int part   = zz & 3;
    const float* __restrict__ src = (zz >> 2) ? k : q;
    const unsigned short* __restrict__ basisF = (const unsigned short*)ws + BF_U;
    float* __restrict__ xp = ws + XP_F + (size_t)(zz * 16 + b) * 65536;

    // dbuf x 12 KB: [0, 4 KB) data f32 [t16][ch64]; [4 KB, 12 KB) basis chunk bf16
    __shared__ __align__(16) unsigned int lds32[2][3072];   // 24 KB

    const int tid  = threadIdx.x;
    const int lane = tid & 63;
    const int wv   = __builtin_amdgcn_readfirstlane(tid >> 6);
    const int wm   = wv >> 1, wc = wv & 1;   // m-half, ch-half
    const int ml   = lane & 31;
    const int khl  = lane >> 5;

    const int srow = tid >> 4;     // staging: t row 0..15
    const int sc4  = tid & 15;     // f4 index within 64 ch
    const float* __restrict__ ap = src + (size_t)b * 2048 * 512 + chtile * 64;

    f32x16 accR, accI;
#pragma unroll
    for (int i = 0; i < 16; ++i) { accR[i] = 0.f; accI[i] = 0.f; }

#define STAGE(BF, C)                                                          \
    {                                                                         \
        unsigned int* db = &lds32[BF][0];                                     \
        gl_lds16(ap + (size_t)(part * 512 + (C) * 16 + srow) * 512 + sc4 * 4, \
                 db + wv * 256);                                              \
        const unsigned short* bch = basisF + (size_t)(part * 32 + (C)) * 4096;\
        gl_lds16(bch + (size_t)tid * 8,         db + 1024 + wv * 256);        \
        gl_lds16(bch + (size_t)(256 + tid) * 8, db + 2048 + wv * 256);        \
    }

#define COMP(BF)                                                              \
    {                                                                         \
        const float* dl = (const float*)&lds32[BF][0];                        \
        const unsigned short* bl = (const unsigned short*)&lds32[BF][1024];   \
        float a[8];                                                           \
        _Pragma("unroll")                                                     \
        for (int e = 0; e < 8; ++e)                                           \
            a[e] = dl[(khl * 8 + e) * 64 + wc * 32 + ml];                     \
        short8v uH, uL;                                                       \
        _Pragma("unroll")                                                     \
        for (int e = 0; e < 8; ++e) {                                         \
            unsigned short hi = bf16_rne(a[e]);                               \
            uH[e] = (short)hi;                                                \
            uL[e] = (short)bf16_rne(a[e] - bf16_f(hi));                       \
        }                                                                     \
        const unsigned short* bb = bl + khl * 512 + (wm * 32 + ml) * 8;       \
        short8v cH = *(const short8v*)(bb);                                   \
        short8v cL = *(const short8v*)(bb + 1024);                            \
        short8v sH = *(const short8v*)(bb + 2048);                            \
        short8v sL = *(const short8v*)(bb + 3072);                            \
        accR = __builtin_amdgcn_mfma_f32_32x32x16_bf16(cH, uH, accR, 0, 0, 0);\
        accR = __builtin_amdgcn_mfma_f32_32x32x16_bf16(cH, uL, accR, 0, 0, 0);\
        accR = __builtin_amdgcn_mfma_f32_32x32x16_bf16(cL, uH, accR, 0, 0, 0);\
        accI = __builtin_amdgcn_mfma_f32_32x32x16_bf16(sH, uH, accI, 0, 0, 0);\
        accI = __builtin_amdgcn_mfma_f32_32x32x16_bf16(sH, uL, accI, 0, 0, 0);\
        accI = __builtin_amdgcn_mfma_f32_32x32x16_bf16(sL, uH, accI, 0, 0, 0);\
    }

    STAGE(0, 0);
    __syncthreads();
    for (int c = 0; c < 32; ++c) {
        if (c + 1 < 32) STAGE((c + 1) & 1, c + 1);
        COMP(c & 1);
        __syncthreads();
    }
#undef STAGE
#undef COMP

    // epilogue: XOR-swizzled LDS transpose (64m x 64ch fp32 = 16 KB) -> [p][h][m][e]
    float* LF = (float*)&lds32[0][0];
#pragma unroll 1
    for (int pass = 0; pass < 2; ++pass) {
        __syncthreads();
#pragma unroll
        for (int reg = 0; reg < 16; ++reg) {
            const int m = wm * 32 + (reg & 3) + 8 * (reg >> 2) + 4 * khl;
            const int chL = wc * 32 + ml;
            LF[m * 64 + (chL ^ ((m & 7) << 3))] = pass ? accI[reg] : accR[reg];
        }
        __syncthreads();
#pragma unroll
        for (int u8 = 0; u8 < 4; ++u8) {
            int unit = tid + u8 * 256;           // 1024 units = m64 x eh2 x h8
            int h = unit & 7, eh = (unit >> 3) & 1, m = unit >> 4;
            float4 val;
#pragma unroll
            for (int j = 0; j < 4; ++j) {
                int chL = (eh * 4 + j) * 8 + h;
                ((float*)&val)[j] = LF[m * 64 + (chL ^ ((m & 7) << 3))];
            }
            *(float4*)&xp[pass * 32768 + (h * 64 + m) * 64 + chtile * 8 + eh * 4] = val;
        }
    }
}

// Middle: per (b,h,x-half). S = Q K (complex), tanh, xqkv, scale -> YT (bf16 split, transposed)
__global__ __launch_bounds__(128) void mid_kernel(float* __restrict__ ws) {
    const int h = blockIdx.x, b = blockIdx.y, xh = blockIdx.z;
    unsigned short* __restrict__ YTb = (unsigned short*)ws + YT_U + (size_t)b * 131072;

    __shared__ float Qs[2][32][64];   // Q [xl][e]; reused as T [xl][y]
    __shared__ float Ksw[2][64][64];  // K [m][e] XOR-swizzled [m][e^m]

    const int tid = threadIdx.x;
    for (int slot = tid; slot < 1024; slot += 128) {   // p2 x 32m x 16f4
        int p = slot >> 9, ml = (slot >> 4) & 31, c4 = slot & 15;
        int off = ((p * 8 + h) * 64 + xh * 32 + ml) * 64 + c4 * 4;
        float4 acc = make_float4(0.f, 0.f, 0.f, 0.f);
#pragma unroll
        for (int part = 0; part < 4; ++part) {
            const float4 v = *(const float4*)(ws + XP_F + (size_t)(part * 16 + b) * 65536 + off);
            acc.x += v.x; acc.y += v.y; acc.z += v.z; acc.w += v.w;
        }
        *(float4*)(&Qs[p][ml][c4 * 4]) = acc;
    }
    for (int slot = tid; slot < 2048; slot += 128) {   // p2 x 64m x 16f4
        int p = slot >> 10, ml = (slot >> 4) & 63, c4 = slot & 15;
        int off = ((p * 8 + h) * 64 + ml) * 64 + c4 * 4;
        float4 acc = make_float4(0.f, 0.f, 0.f, 0.f);
#pragma unroll
        for (int part = 0; part < 4; ++part) {
            const float4 v = *(const float4*)(ws + XP_F + (size_t)((4 + part) * 16 + b) * 65536 + off);
            acc.x += v.x; acc.y += v.y; acc.z += v.z; acc.w += v.w;
        }
        Ksw[p][ml][(c4 * 4 + 0) ^ ml] = acc.x;
        Ksw[p][ml][(c4 * 4 + 1) ^ ml] = acc.y;
        Ksw[p][ml][(c4 * 4 + 2) ^ ml] = acc.z;
        Ksw[p][ml][(c4 * 4 + 3) ^ ml] = acc.w;
    }
    __syncthreads();

    const int lane = tid & 63;
    const int wid  = tid >> 6;
    const int xb   = wid * 16;

    float sr[16], si[16];
#pragma unroll
    for (int i = 0; i < 16; ++i) { sr[i] = 0.f; si[i] = 0.f; }
    const int y = lane;
    for (int e = 0; e < 64; ++e) {
        float kr = Ksw[0][y][e ^ y];
        float ki = Ksw[1][y][e ^ y];
#pragma unroll
        for (int i = 0; i < 16; ++i) {
            float qr = Qs[0][xb + i][e];
            float qi = Qs[1][xb + i][e];
            sr[i] += qr * kr; sr[i] -= qi * ki;
            si[i] += qr * ki; si[i] += qi * kr;
        }
    }
    float tr[16], ti[16];
#pragma unroll
    for (int i = 0; i < 16; ++i) { tr[i] = tanhf(sr[i]); ti[i] = tanhf(si[i]); }
    __syncthreads();
#pragma unroll
    for (int i = 0; i < 16; ++i) {
        Qs[0][xb + i][y] = tr[i];
        Qs[1][xb + i][y] = ti[i];
    }
    __syncthreads();

    float vr[16], vi[16];
#pragma unroll
    for (int i = 0; i < 16; ++i) { vr[i] = 0.f; vi[i] = 0.f; }
    const int e = lane;
    for (int yy = 0; yy < 64; ++yy) {
        float kr = Ksw[0][yy][e ^ yy];
        float ki = Ksw[1][yy][e ^ yy];
#pragma unroll
        for (int i = 0; i < 16; ++i) {
            float trr = Qs[0][xb + i][yy];
            float tii = Qs[1][xb + i][yy];
            vr[i] += trr * kr; vr[i] -= tii * ki;
            vi[i] += trr * ki; vi[i] += tii * kr;
        }
    }
#pragma unroll
    for (int i = 0; i < 16; ++i) {
        int x = xh * 32 + xb + i;
        float f = (x == 0 ? 1.0f : 2.0f) * (1.0f / (2048.0f * 4096.0f));
        float yr = f * vr[i];
        float yi = -f * vi[i];     // sign folded: out = P + Q with +sin table
        int off = (h * 64 + e) * 64 + x;
        unsigned short rH = bf16_rne(yr), iH = bf16_rne(yi);
        YTb[off]         = rH;
        YTb[32768 + off] = bf16_rne(yr - bf16_f(rH));
        YTb[65536 + off] = iH;
        YTb[98304 + off] = bf16_rne(yi - bf16_f(iH));
    }
}

// Inverse folded DFT via bf16-split MFMA. Block: 64t x 128ch; 4 waves (wt2 x wcc2),
// wave = 32t x 64ch (2 accs/side). Y staged in LDS from YT (m-slabs of 16, dbuf).
// P=sum cos*Yr, Q=sum sin*Yi; out[t]=P+Q (t<=1024), out[2048-t]=P-Q (1<=t<=1023).
__global__ __launch_bounds__(256, 3) void idft_kernel(const float* __restrict__ ws,
                                                      float* __restrict__ out) {
    const int tt0    = blockIdx.x * 64;   // 0..1024
    const int chtile = blockIdx.y;        // 0..3
    const int b      = blockIdx.z;
    const unsigned short* __restrict__ basisI = (const unsigned short*)ws + BI_U;
    const unsigned short* __restrict__ YTb = (const unsigned short*)ws + YT_U + (size_t)b * 131072;

    // [tbl4][ch128][24] per buffer = 12288 ushorts (stride 24 for alignment + banks)
    __shared__ __align__(16) unsigned short ldsY[2][12288];   // 48 KB

    const int tid  = threadIdx.x;
    const int lane = tid & 63;
    const int wv   = tid >> 6;
    const int wt   = wv >> 1, wcc = wv & 1;
    const int ml   = lane & 31;
    const int khl  = lane >> 5;

    f32x16 accP0, accP1, accQ0, accQ1;
#pragma unroll
    for (int i = 0; i < 16; ++i) { accP0[i] = 0.f; accP1[i] = 0.f; accQ0[i] = 0.f; accQ1[i] = 0.f; }

    const int tblA = tid >> 7;            // staging row A: tables 0,1
    const int chlA = tid & 127;
    short8v sA0, sA1, sB0, sB1;

    auto LOAD = [&](int s) {
        const unsigned short* gA = YTb + tblA * 32768 + (chtile * 128 + chlA) * 64 + s * 16;
        const unsigned short* gB = gA + 2 * 32768;      // tables 2,3
        sA0 = *(const short8v*)(gA);
        sA1 = *(const short8v*)(gA + 8);
        sB0 = *(const short8v*)(gB);
        sB1 = *(const short8v*)(gB + 8);
    };
    auto WRITE = [&](int bf) {
        unsigned short* D = &ldsY[bf][0];
        const int offA = tblA * 3072 + chlA * 24;
        *(short8v*)(D + offA)            = sA0;
        *(short8v*)(D + offA + 8)        = sA1;
        *(short8v*)(D + offA + 2 * 3072)     = sB0;
        *(short8v*)(D + offA + 2 * 3072 + 8) = sB1;
    };
    auto COMP = [&](int bf, int s) {
        const unsigned short* bb = basisI + (s * 8 + khl) * 8704 + (tt0 + wt * 32 + ml) * 8;
        short8v cH = *(const short8v*)(bb);
        short8v cL = *(const short8v*)(bb + 17408);
        short8v sH = *(const short8v*)(bb + 34816);
        short8v sL = *(const short8v*)(bb + 52224);
        const unsigned short* L = &ldsY[bf][0];
        const int b0 = (wcc * 64 + ml) * 24 + khl * 8;
        short8v yrH0 = *(const short8v*)(L + b0);
        short8v yrL0 = *(const short8v*)(L + 3072 + b0);
        short8v yiH0 = *(const short8v*)(L + 6144 + b0);
        short8v yiL0 = *(const short8v*)(L + 9216 + b0);
        const int b1 = b0 + 32 * 24;
        short8v yrH1 = *(const short8v*)(L + b1);
        short8v yrL1 = *(const short8v*)(L + 3072 + b1);
        short8v yiH1 = *(const short8v*)(L + 6144 + b1);
        short8v yiL1 = *(const short8v*)(L + 9216 + b1);
        accP0 = __builtin_amdgcn_mfma_f32_32x32x16_bf16(cH, yrH0, accP0, 0, 0, 0);
        accP0 = __builtin_amdgcn_mfma_f32_32x32x16_bf16(cH, yrL0, accP0, 0, 0, 0);
        accP0 = __builtin_amdgcn_mfma_f32_32x32x16_bf16(cL, yrH0, accP0, 0, 0, 0);
        accQ0 = __builtin_amdgcn_mfma_f32_32x32x16_bf16(sH, yiH0, accQ0, 0, 0, 0);
        accQ0 = __builtin_amdgcn_mfma_f32_32x32x16_bf16(sH, yiL0, accQ0, 0, 0, 0);
        accQ0 = __builtin_amdgcn_mfma_f32_32x32x16_bf16(sL, yiH0, accQ0, 0, 0, 0);
        accP1 = __builtin_amdgcn_mfma_f32_32x32x16_bf16(cH, yrH1, accP1, 0, 0, 0);
        accP1 = __builtin_amdgcn_mfma_f32_32x32x16_bf16(cH, yrL1, accP1, 0, 0, 0);
        accP1 = __builtin_amdgcn_mfma_f32_32x32x16_bf16(cL, yrH1, accP1, 0, 0, 0);
        accQ1 = __builtin_amdgcn_mfma_f32_32x32x16_bf16(sH, yiH1, accQ1, 0, 0, 0);
        accQ1 = __builtin_amdgcn_mfma_f32_32x32x16_bf16(sH, yiL1, accQ1, 0, 0, 0);
        accQ1 = __builtin_amdgcn_mfma_f32_32x32x16_bf16(sL, yiH1, accQ1, 0, 0, 0);
    };

    LOAD(0); WRITE(0); __syncthreads();
    for (int s = 0; s < 4; ++s) {
        if (s < 3) LOAD(s + 1);
        COMP(s & 1, s);
        if (s < 3) { WRITE((s + 1) & 1); __syncthreads(); }
    }

    float* __restrict__ ob = out + (size_t)b * 2048 * 512;
#pragma unroll
    for (int reg = 0; reg < 16; ++reg) {
        const int tL = wt * 32 + (reg & 3) + 8 * (reg >> 2) + 4 * khl;
        const int t  = tt0 + tL;
        const int ch0 = chtile * 128 + wcc * 64 + ml;
        float p0 = accP0[reg], q0 = accQ0[reg];
        float p1 = accP1[reg], q1 = accQ1[reg];
        if (t <= 1024) {
            ob[(size_t)t * 512 + ch0]      = p0 + q0;
            ob[(size_t)t * 512 + ch0 + 32] = p1 + q1;
        }
        if (t >= 1 && t <= 1023) {
            ob[(size_t)(2048 - t) * 512 + ch0]      = p0 - q0;
            ob[(size_t)(2048 - t) * 512 + ch0 + 32] = p1 - q1;
        }
    }
}

extern "C" void kernel_launch(void* const* d_in, const int* in_sizes, int n_in,
                              void* d_out, int out_size, void* d_ws, size_t ws_size,
                              hipStream_t stream) {
    const float* q = (const float*)d_in[0];
    const float* k = (const float*)d_in[1];
    float* ws = (float*)d_ws;      // ~39.4 MB used
    float* out = (float*)d_out;

    hipLaunchKernelGGL(basis_kernel, dim3(512), dim3(256), 0, stream, ws);
    hipLaunchKernelGGL(fdft_kernel, dim3(8, 16, 8), dim3(256), 0, stream, q, k, ws);
    hipLaunchKernelGGL(mid_kernel, dim3(8, 16, 2), dim3(128), 0, stream, ws);
    hipLaunchKernelGGL(idft_kernel, dim3(17, 4, 16), dim3(256), 0, stream, ws, out);
}

// Round 15
// 117.677 us; speedup vs baseline: 1.0036x; 1.0036x over previous
//
#include <hip/hip_runtime.h>
#include <math.h>

typedef __attribute__((ext_vector_type(8))) short short8v;   // 8 bf16
typedef __attribute__((ext_vector_type(16))) float f32x16;   // MFMA acc

// ws layout:
//  ushort offsets:
//   basisF (fdft) [cc128][tbl4][kh2][m64][e8]    @ u 0        (524288 u)
//     tbl: 0=cosHi 1=cosLo 2=(-sin)Hi 3=(-sin)Lo ; t = cc*16 + kh*8 + e
//   basisI (idft) [slab4][tbl4][kh2][t1088][e8]  @ u 524288   (278528 u)
//     tbl: 0=cosHi 1=cosLo 2=sinHi 3=sinLo ; m = slab*16 + kh*8 + e
//  float offsets:
//   XP [zz8][b16][p2][h8][m64][e64]              @ f 401408   (8388608 f)
//  ushort offsets:
//   YT [b16][tbl4][ch512][m64]                   @ u 17580032 (2097152 u)
//     tbl: 0=YrHi 1=YrLo 2=YiHi 3=YiLo (Yi sign-folded)
#define BF_U 0
#define BI_U 524288
#define XP_F 401408
#define YT_U 17580032

__device__ inline unsigned short bf16_rne(float x) {
    unsigned int u = __float_as_uint(x);
    u += 0x7FFFu + ((u >> 16) & 1u);
    return (unsigned short)(u >> 16);
}
__device__ inline float bf16_f(unsigned short h) {
    return __uint_as_float(((unsigned int)h) << 16);
}

// async global->LDS, 16 B per lane; l must be wave-uniform, g per-lane.
__device__ inline void gl_lds16(const void* g, void* l) {
    __builtin_amdgcn_global_load_lds(
        (const __attribute__((address_space(1))) unsigned int*)g,
        (__attribute__((address_space(3))) unsigned int*)l, 16, 0, 0);
}

__global__ __launch_bounds__(256) void basis_kernel(float* __restrict__ w) {
    int idx = blockIdx.x * 256 + threadIdx.x;
    const float th = 0.0030679615757712823f; // 2*pi/2048
    unsigned short* bw = (unsigned short*)w;
    if (idx < 131072) {          // fdft tables: t 0..2047, m 0..63
        int t = idx >> 6, m = idx & 63;
        int j = (m * t) & 2047;
        float s, c; sincosf(th * (float)j, &s, &c);
        float ns = -s;
        int cc = t >> 4, kh = (t >> 3) & 1, e = t & 7;
        int base = BF_U + cc * 4096 + kh * 512 + m * 8 + e;
        unsigned short chv = bf16_rne(c), shv = bf16_rne(ns);
        bw[base]        = chv;
        bw[base + 1024] = bf16_rne(c - bf16_f(chv));
        bw[base + 2048] = shv;
        bw[base + 3072] = bf16_rne(ns - bf16_f(shv));
    }
    if (idx < 69632) {           // idft tables
        int m = idx / 1088, t = idx - m * 1088;
        int j = (m * t) & 2047;
        float s, c; sincosf(th * (float)j, &s, &c);
        int slab = m >> 4, kh = (m >> 3) & 1, e = m & 7;
        int base = BI_U + (slab * 8 + kh) * 8704 + t * 8 + e;
        unsigned short chv = bf16_rne(c), shv = bf16_rne(s);
        bw[base]         = chv;
        bw[base + 17408] = bf16_rne(c - bf16_f(chv));
        bw[base + 34816] = shv;
        bw[base + 52224] = bf16_rne(s - bf16_f(shv));
    }
}

// Forward (UNFOLDED) DFT via bf16-split MFMA, global_load_lds staging with
// COUNTED vmcnt + raw s_barrier (T3/T4): prefetch loads stay in flight across
// the barrier. Block: 64m x 64ch x one t-quarter; 4 waves = (m-half x ch-half).
// Grid (chtile8, b16, zz8) = 1024 blocks.
__global__ __launch_bounds__(256, 4) void fdft_kernel(const float* __restrict__ q,
                                                      const float* __restrict__ k,
                                                      float* __restrict__ ws) {
    const int chtile = blockIdx.x;        // 0..7 (64 ch)
    const int b      = blockIdx.y;
    const int zz     = blockIdx.z;        // tz*4 + part
    const int part   = zz & 3;
    const float* __restrict__ src = (zz >> 2) ? k : q;
    const unsigned short* __restrict__ basisF = (const unsigned short*)ws + BF_U;
    float* __restrict__ xp = ws + XP_F + (size_t)(zz * 16 + b) * 65536;

    // dbuf x 12 KB: [0, 4 KB) data f32 [t16][ch64]; [4 KB, 12 KB) basis chunk bf16
    __shared__ __align__(16) unsigned int lds32[2][3072];   // 24 KB

    const int tid  = threadIdx.x;
    const int lane = tid & 63;
    const int wv   = __builtin_amdgcn_readfirstlane(tid >> 6);
    const int wm   = wv >> 1, wc = wv & 1;   // m-half, ch-half
    const int ml   = lane & 31;
    const int khl  = lane >> 5;

    const int srow = tid >> 4;     // staging: t row 0..15
    const int sc4  = tid & 15;     // f4 index within 64 ch
    const float* __restrict__ ap = src + (size_t)b * 2048 * 512 + chtile * 64;

    f32x16 accR, accI;
#pragma unroll
    for (int i = 0; i < 16; ++i) { accR[i] = 0.f; accI[i] = 0.f; }

#define STAGE(BF, C)                                                          \
    {                                                                         \
        unsigned int* db = &lds32[BF][0];                                     \
        gl_lds16(ap + (size_t)(part * 512 + (C) * 16 + srow) * 512 + sc4 * 4, \
                 db + wv * 256);                                              \
        const unsigned short* bch = basisF + (size_t)(part * 32 + (C)) * 4096;\
        gl_lds16(bch + (size_t)tid * 8,         db + 1024 + wv * 256);        \
        gl_lds16(bch + (size_t)(256 + tid) * 8, db + 2048 + wv * 256);        \
    }

#define COMP(BF)                                                              \
    {                                                                         \
        const float* dl = (const float*)&lds32[BF][0];                        \
        const unsigned short* bl = (const unsigned short*)&lds32[BF][1024];   \
        float a[8];                                                           \
        _Pragma("unroll")                                                     \
        for (int e = 0; e < 8; ++e)                                           \
            a[e] = dl[(khl * 8 + e) * 64 + wc * 32 + ml];                     \
        short8v uH, uL;                                                       \
        _Pragma("unroll")                                                     \
        for (int e = 0; e < 8; ++e) {                                         \
            unsigned short hi = bf16_rne(a[e]);                               \
            uH[e] = (short)hi;                                                \
            uL[e] = (short)bf16_rne(a[e] - bf16_f(hi));                       \
        }                                                                     \
        const unsigned short* bb = bl + khl * 512 + (wm * 32 + ml) * 8;       \
        short8v cH = *(const short8v*)(bb);                                   \
        short8v cL = *(const short8v*)(bb + 1024);                            \
        short8v sH = *(const short8v*)(bb + 2048);                            \
        short8v sL = *(const short8v*)(bb + 3072);                            \
        accR = __builtin_amdgcn_mfma_f32_32x32x16_bf16(cH, uH, accR, 0, 0, 0);\
        accR = __builtin_amdgcn_mfma_f32_32x32x16_bf16(cH, uL, accR, 0, 0, 0);\
        accR = __builtin_amdgcn_mfma_f32_32x32x16_bf16(cL, uH, accR, 0, 0, 0);\
        accI = __builtin_amdgcn_mfma_f32_32x32x16_bf16(sH, uH, accI, 0, 0, 0);\
        accI = __builtin_amdgcn_mfma_f32_32x32x16_bf16(sH, uL, accI, 0, 0, 0);\
        accI = __builtin_amdgcn_mfma_f32_32x32x16_bf16(sL, uH, accI, 0, 0, 0);\
    }

    STAGE(0, 0);
    for (int c = 0; c < 32; ++c) {
        if (c + 1 < 32) {
            STAGE((c + 1) & 1, c + 1);
            // wait chunk c's 3 loads only; chunk c+1's 3 stay in flight
            asm volatile("s_waitcnt vmcnt(3)" ::: "memory");
        } else {
            asm volatile("s_waitcnt vmcnt(0)" ::: "memory");
        }
        __builtin_amdgcn_sched_barrier(0);
        __builtin_amdgcn_s_barrier();      // chunk c visible to all waves
        COMP(c & 1);
        __builtin_amdgcn_s_barrier();      // all waves done reading buf c
    }
#undef STAGE
#undef COMP

    // epilogue: XOR-swizzled LDS transpose (64m x 64ch fp32 = 16 KB) -> [p][h][m][e]
    float* LF = (float*)&lds32[0][0];
#pragma unroll 1
    for (int pass = 0; pass < 2; ++pass) {
        __syncthreads();
#pragma unroll
        for (int reg = 0; reg < 16; ++reg) {
            const int m = wm * 32 + (reg & 3) + 8 * (reg >> 2) + 4 * khl;
            const int chL = wc * 32 + ml;
            LF[m * 64 + (chL ^ ((m & 7) << 3))] = pass ? accI[reg] : accR[reg];
        }
        __syncthreads();
#pragma unroll
        for (int u8 = 0; u8 < 4; ++u8) {
            int unit = tid + u8 * 256;           // 1024 units = m64 x eh2 x h8
            int h = unit & 7, eh = (unit >> 3) & 1, m = unit >> 4;
            float4 val;
#pragma unroll
            for (int j = 0; j < 4; ++j) {
                int chL = (eh * 4 + j) * 8 + h;
                ((float*)&val)[j] = LF[m * 64 + (chL ^ ((m & 7) << 3))];
            }
            *(float4*)&xp[pass * 32768 + (h * 64 + m) * 64 + chtile * 8 + eh * 4] = val;
        }
    }
}

// Middle: per (b,h,x-half). S = Q K (complex), tanh, xqkv, scale -> YT (bf16 split, transposed)
__global__ __launch_bounds__(128) void mid_kernel(float* __restrict__ ws) {
    const int h = blockIdx.x, b = blockIdx.y, xh = blockIdx.z;
    unsigned short* __restrict__ YTb = (unsigned short*)ws + YT_U + (size_t)b * 131072;

    __shared__ float Qs[2][32][64];   // Q [xl][e]; reused as T [xl][y]
    __shared__ float Ksw[2][64][64];  // K [m][e] XOR-swizzled [m][e^m]

    const int tid = threadIdx.x;
    for (int slot = tid; slot < 1024; slot += 128) {   // p2 x 32m x 16f4
        int p = slot >> 9, ml = (slot >> 4) & 31, c4 = slot & 15;
        int off = ((p * 8 + h) * 64 + xh * 32 + ml) * 64 + c4 * 4;
        float4 acc = make_float4(0.f, 0.f, 0.f, 0.f);
#pragma unroll
        for (int part = 0; part < 4; ++part) {
            const float4 v = *(const float4*)(ws + XP_F + (size_t)(part * 16 + b) * 65536 + off);
            acc.x += v.x; acc.y += v.y; acc.z += v.z; acc.w += v.w;
        }
        *(float4*)(&Qs[p][ml][c4 * 4]) = acc;
    }
    for (int slot = tid; slot < 2048; slot += 128) {   // p2 x 64m x 16f4
        int p = slot >> 10, ml = (slot >> 4) & 63, c4 = slot & 15;
        int off = ((p * 8 + h) * 64 + ml) * 64 + c4 * 4;
        float4 acc = make_float4(0.f, 0.f, 0.f, 0.f);
#pragma unroll
        for (int part = 0; part < 4; ++part) {
            const float4 v = *(const float4*)(ws + XP_F + (size_t)((4 + part) * 16 + b) * 65536 + off);
            acc.x += v.x; acc.y += v.y; acc.z += v.z; acc.w += v.w;
        }
        Ksw[p][ml][(c4 * 4 + 0) ^ ml] = acc.x;
        Ksw[p][ml][(c4 * 4 + 1) ^ ml] = acc.y;
        Ksw[p][ml][(c4 * 4 + 2) ^ ml] = acc.z;
        Ksw[p][ml][(c4 * 4 + 3) ^ ml] = acc.w;
    }
    __syncthreads();

    const int lane = tid & 63;
    const int wid  = tid >> 6;
    const int xb   = wid * 16;

    float sr[16], si[16];
#pragma unroll
    for (int i = 0; i < 16; ++i) { sr[i] = 0.f; si[i] = 0.f; }
    const int y = lane;
    for (int e = 0; e < 64; ++e) {
        float kr = Ksw[0][y][e ^ y];
        float ki = Ksw[1][y][e ^ y];
#pragma unroll
        for (int i = 0; i < 16; ++i) {
            float qr = Qs[0][xb + i][e];
            float qi = Qs[1][xb + i][e];
            sr[i] += qr * kr; sr[i] -= qi * ki;
            si[i] += qr * ki; si[i] += qi * kr;
        }
    }
    float tr[16], ti[16];
#pragma unroll
    for (int i = 0; i < 16; ++i) { tr[i] = tanhf(sr[i]); ti[i] = tanhf(si[i]); }
    __syncthreads();
#pragma unroll
    for (int i = 0; i < 16; ++i) {
        Qs[0][xb + i][y] = tr[i];
        Qs[1][xb + i][y] = ti[i];
    }
    __syncthreads();

    float vr[16], vi[16];
#pragma unroll
    for (int i = 0; i < 16; ++i) { vr[i] = 0.f; vi[i] = 0.f; }
    const int e = lane;
    for (int yy = 0; yy < 64; ++yy) {
        float kr = Ksw[0][yy][e ^ yy];
        float ki = Ksw[1][yy][e ^ yy];
#pragma unroll
        for (int i = 0; i < 16; ++i) {
            float trr = Qs[0][xb + i][yy];
            float tii = Qs[1][xb + i][yy];
            vr[i] += trr * kr; vr[i] -= tii * ki;
            vi[i] += trr * ki; vi[i] += tii * kr;
        }
    }
#pragma unroll
    for (int i = 0; i < 16; ++i) {
        int x = xh * 32 + xb + i;
        float f = (x == 0 ? 1.0f : 2.0f) * (1.0f / (2048.0f * 4096.0f));
        float yr = f * vr[i];
        float yi = -f * vi[i];     // sign folded: out = P + Q with +sin table
        int off = (h * 64 + e) * 64 + x;
        unsigned short rH = bf16_rne(yr), iH = bf16_rne(yi);
        YTb[off]         = rH;
        YTb[32768 + off] = bf16_rne(yr - bf16_f(rH));
        YTb[65536 + off] = iH;
        YTb[98304 + off] = bf16_rne(yi - bf16_f(iH));
    }
}

// Inverse folded DFT via bf16-split MFMA. Block: 64t x 128ch; 4 waves (wt2 x wcc2),
// wave = 32t x 64ch (2 accs/side). Y staged in LDS from YT (m-slabs of 16, dbuf).
// P=sum cos*Yr, Q=sum sin*Yi; out[t]=P+Q (t<=1024), out[2048-t]=P-Q (1<=t<=1023).
__global__ __launch_bounds__(256, 3) void idft_kernel(const float* __restrict__ ws,
                                                      float* __restrict__ out) {
    const int tt0    = blockIdx.x * 64;   // 0..1024
    const int chtile = blockIdx.y;        // 0..3
    const int b      = blockIdx.z;
    const unsigned short* __restrict__ basisI = (const unsigned short*)ws + BI_U;
    const unsigned short* __restrict__ YTb = (const unsigned short*)ws + YT_U + (size_t)b * 131072;

    // [tbl4][ch128][24] per buffer = 12288 ushorts (stride 24 for alignment + banks)
    __shared__ __align__(16) unsigned short ldsY[2][12288];   // 48 KB

    const int tid  = threadIdx.x;
    const int lane = tid & 63;
    const int wv   = tid >> 6;
    const int wt   = wv >> 1, wcc = wv & 1;
    const int ml   = lane & 31;
    const int khl  = lane >> 5;

    f32x16 accP0, accP1, accQ0, accQ1;
#pragma unroll
    for (int i = 0; i < 16; ++i) { accP0[i] = 0.f; accP1[i] = 0.f; accQ0[i] = 0.f; accQ1[i] = 0.f; }

    const int tblA = tid >> 7;            // staging row A: tables 0,1
    const int chlA = tid & 127;
    short8v sA0, sA1, sB0, sB1;

    auto LOAD = [&](int s) {
        const unsigned short* gA = YTb + tblA * 32768 + (chtile * 128 + chlA) * 64 + s * 16;
        const unsigned short* gB = gA + 2 * 32768;      // tables 2,3
        sA0 = *(const short8v*)(gA);
        sA1 = *(const short8v*)(gA + 8);
        sB0 = *(const short8v*)(gB);
        sB1 = *(const short8v*)(gB + 8);
    };
    auto WRITE = [&](int bf) {
        unsigned short* D = &ldsY[bf][0];
        const int offA = tblA * 3072 + chlA * 24;
        *(short8v*)(D + offA)            = sA0;
        *(short8v*)(D + offA + 8)        = sA1;
        *(short8v*)(D + offA + 2 * 3072)     = sB0;
        *(short8v*)(D + offA + 2 * 3072 + 8) = sB1;
    };
    auto COMP = [&](int bf, int s) {
        const unsigned short* bb = basisI + (s * 8 + khl) * 8704 + (tt0 + wt * 32 + ml) * 8;
        short8v cH = *(const short8v*)(bb);
        short8v cL = *(const short8v*)(bb + 17408);
        short8v sH = *(const short8v*)(bb + 34816);
        short8v sL = *(const short8v*)(bb + 52224);
        const unsigned short* L = &ldsY[bf][0];
        const int b0 = (wcc * 64 + ml) * 24 + khl * 8;
        short8v yrH0 = *(const short8v*)(L + b0);
        short8v yrL0 = *(const short8v*)(L + 3072 + b0);
        short8v yiH0 = *(const short8v*)(L + 6144 + b0);
        short8v yiL0 = *(const short8v*)(L + 9216 + b0);
        const int b1 = b0 + 32 * 24;
        short8v yrH1 = *(const short8v*)(L + b1);
        short8v yrL1 = *(const short8v*)(L + 3072 + b1);
        short8v yiH1 = *(const short8v*)(L + 6144 + b1);
        short8v yiL1 = *(const short8v*)(L + 9216 + b1);
        accP0 = __builtin_amdgcn_mfma_f32_32x32x16_bf16(cH, yrH0, accP0, 0, 0, 0);
        accP0 = __builtin_amdgcn_mfma_f32_32x32x16_bf16(cH, yrL0, accP0, 0, 0, 0);
        accP0 = __builtin_amdgcn_mfma_f32_32x32x16_bf16(cL, yrH0, accP0, 0, 0, 0);
        accQ0 = __builtin_amdgcn_mfma_f32_32x32x16_bf16(sH, yiH0, accQ0, 0, 0, 0);
        accQ0 = __builtin_amdgcn_mfma_f32_32x32x16_bf16(sH, yiL0, accQ0, 0, 0, 0);
        accQ0 = __builtin_amdgcn_mfma_f32_32x32x16_bf16(sL, yiH0, accQ0, 0, 0, 0);
        accP1 = __builtin_amdgcn_mfma_f32_32x32x16_bf16(cH, yrH1, accP1, 0, 0, 0);
        accP1 = __builtin_amdgcn_mfma_f32_32x32x16_bf16(cH, yrL1, accP1, 0, 0, 0);
        accP1 = __builtin_amdgcn_mfma_f32_32x32x16_bf16(cL, yrH1, accP1, 0, 0, 0);
        accQ1 = __builtin_amdgcn_mfma_f32_32x32x16_bf16(sH, yiH1, accQ1, 0, 0, 0);
        accQ1 = __builtin_amdgcn_mfma_f32_32x32x16_bf16(sH, yiL1, accQ1, 0, 0, 0);
        accQ1 = __builtin_amdgcn_mfma_f32_32x32x16_bf16(sL, yiH1, accQ1, 0, 0, 0);
    };

    LOAD(0); WRITE(0); __syncthreads();
    for (int s = 0; s < 4; ++s) {
        if (s < 3) LOAD(s + 1);
        COMP(s & 1, s);
        if (s < 3) { WRITE((s + 1) & 1); __syncthreads(); }
    }

    float* __restrict__ ob = out + (size_t)b * 2048 * 512;
#pragma unroll
    for (int reg = 0; reg < 16; ++reg) {
        const int tL = wt * 32 + (reg & 3) + 8 * (reg >> 2) + 4 * khl;
        const int t  = tt0 + tL;
        const int ch0 = chtile * 128 + wcc * 64 + ml;
        float p0 = accP0[reg], q0 = accQ0[reg];
        float p1 = accP1[reg], q1 = accQ1[reg];
        if (t <= 1024) {
            ob[(size_t)t * 512 + ch0]      = p0 + q0;
            ob[(size_t)t * 512 + ch0 + 32] = p1 + q1;
        }
        if (t >= 1 && t <= 1023) {
            ob[(size_t)(2048 - t) * 512 + ch0]      = p0 - q0;
            ob[(size_t)(2048 - t) * 512 + ch0 + 32] = p1 - q1;
        }
    }
}

extern "C" void kernel_launch(void* const* d_in, const int* in_sizes, int n_in,
                              void* d_out, int out_size, void* d_ws, size_t ws_size,
                              hipStream_t stream) {
    const float* q = (const float*)d_in[0];
    const float* k = (const float*)d_in[1];
    float* ws = (float*)d_ws;      // ~39.4 MB used
    float* out = (float*)d_out;

    hipLaunchKernelGGL(basis_kernel, dim3(512), dim3(256), 0, stream, ws);
    hipLaunchKernelGGL(fdft_kernel, dim3(8, 16, 8), dim3(256), 0, stream, q, k, ws);
    hipLaunchKernelGGL(mid_kernel, dim3(8, 16, 2), dim3(128), 0, stream, ws);
    hipLaunchKernelGGL(idft_kernel, dim3(17, 4, 16), dim3(256), 0, stream, ws, out);
}